// Round 10
// baseline (434.418 us; speedup 1.0000x reference)
//
#include <hip/hip_runtime.h>
#include <hip/hip_bf16.h>
#include <stdint.h>
#include <math.h>

#define NN 8192        // nodes
#define NE 262144      // edges
#define WPR 256        // 32-bit words per dense adjacency row

struct TFKey { uint32_t a, b; };

// JAX threefry2x32 (rot 13,15,26,6 / 17,29,16,24; 20 rounds)
__host__ __device__ static inline void tf2x32(uint32_t k0, uint32_t k1,
                                              uint32_t x0, uint32_t x1,
                                              uint32_t* o0, uint32_t* o1) {
  uint32_t ks2 = k0 ^ k1 ^ 0x1BD11BDAu;
#define TF_ROT(x, r) (((x) << (r)) | ((x) >> (32 - (r))))
#define TF_R(r) { x0 += x1; x1 = TF_ROT(x1, r); x1 ^= x0; }
  x0 += k0; x1 += k1;
  TF_R(13) TF_R(15) TF_R(26) TF_R(6)
  x0 += k1;  x1 += ks2 + 1u;
  TF_R(17) TF_R(29) TF_R(16) TF_R(24)
  x0 += ks2; x1 += k0 + 2u;
  TF_R(13) TF_R(15) TF_R(26) TF_R(6)
  x0 += k0;  x1 += k1 + 3u;
  TF_R(17) TF_R(29) TF_R(16) TF_R(24)
  x0 += k1;  x1 += ks2 + 4u;
  TF_R(13) TF_R(15) TF_R(26) TF_R(6)
  x0 += ks2; x1 += k0 + 5u;
  *o0 = x0; *o1 = x1;
#undef TF_R
#undef TF_ROT
}

// JAX partitionable 32-bit random_bits at flat index n: bits = o0^o1 @ (0,n);
// uniform f32 = bitcast((bits>>9)|0x3f800000) - 1.0f  (exact 2^-23 grid)
__device__ static inline float tf_uniform(TFKey k, uint32_t n) {
  uint32_t o0, o1;
  tf2x32(k.a, k.b, 0u, n, &o0, &o1);
  uint32_t bits = o0 ^ o1;
  return __uint_as_float((bits >> 9) | 0x3f800000u) - 1.0f;
}

// ---- probe edge_index storage: int64 (all vals < 8192) vs int32 ----
__global__ __launch_bounds__(256) void k_probe(const int* __restrict__ e,
                                               uint32_t* __restrict__ flag) {
  int idx = blockIdx.x * 256 + threadIdx.x;
  const unsigned long long* p = (const unsigned long long*)e;
  bool bad = p[idx] >= 8192ull;
  if (__ballot(bad)) { if ((threadIdx.x & 63) == 0) atomicOr(flag, 1u); }
}

// ---- dense binary adjacency bitmask (dedupes duplicate edges) ----
__global__ __launch_bounds__(256) void k_build(const int* __restrict__ e,
                                               const uint32_t* __restrict__ flag,
                                               uint32_t* __restrict__ dense) {
  int ed = blockIdx.x * 256 + threadIdx.x;
  int r, c;
  if (*flag) { r = e[ed]; c = e[ed + NE]; }
  else { const long long* p = (const long long*)e; r = (int)p[ed]; c = (int)p[ed + NE]; }
  atomicOr(&dense[(size_t)r * WPR + (c >> 5)], 1u << (c & 31));
}

// ---- deg[i] = popcount(dense row i); wave-per-row ----
__global__ __launch_bounds__(256) void k_deg(const uint32_t* __restrict__ dense,
                                             uint32_t* __restrict__ deg) {
  int lane = threadIdx.x & 63;
  int i = blockIdx.x * 4 + (threadIdx.x >> 6);
  const uint4* row = (const uint4*)(dense + (size_t)i * WPR);
  uint4 v = row[lane];
  int c = __popc(v.x) + __popc(v.y) + __popc(v.z) + __popc(v.w);
  for (int s = 32; s; s >>= 1) c += __shfl_xor(c, s, 64);
  if (lane == 0) deg[i] = (uint32_t)c;
}

// ---- exclusive scan of deg[8192] -> rowptr[8193]; single block ----
__global__ __launch_bounds__(256) void k_scan(const uint32_t* __restrict__ deg,
                                              uint32_t* __restrict__ rowptr) {
  __shared__ uint32_t part[256];
  int t = threadIdx.x;
  uint32_t loc[32];
  uint32_t s = 0;
  for (int k = 0; k < 32; ++k) { loc[k] = s; s += deg[t * 32 + k]; }
  part[t] = s;
  __syncthreads();
  for (int off = 1; off < 256; off <<= 1) {
    uint32_t v = (t >= off) ? part[t - off] : 0u;
    __syncthreads();
    part[t] += v;
    __syncthreads();
  }
  uint32_t base = (t == 0) ? 0u : part[t - 1];
  for (int k = 0; k < 32; ++k) rowptr[t * 32 + k] = base + loc[k];
  if (t == 255) rowptr[8192] = part[255];
}

// ---- CSR cols from dense bitmask; wave-per-row, ascending cols ----
__global__ __launch_bounds__(256) void k_fill(const uint32_t* __restrict__ dense,
                                              const uint32_t* __restrict__ rowptr,
                                              uint16_t* __restrict__ cols) {
  int lane = threadIdx.x & 63;
  int i = blockIdx.x * 4 + (threadIdx.x >> 6);
  const uint4* row = (const uint4*)(dense + (size_t)i * WPR);
  uint4 v = row[lane];
  uint32_t w[4] = { v.x, v.y, v.z, v.w };
  int cnt = __popc(w[0]) + __popc(w[1]) + __popc(w[2]) + __popc(w[3]);
  int pre = cnt;
  for (int s = 1; s < 64; s <<= 1) {
    int o = __shfl_up(pre, s, 64);
    if (lane >= s) pre += o;
  }
  pre -= cnt;
  uint32_t pos = rowptr[i] + (uint32_t)pre;
  for (int wi = 0; wi < 4; ++wi) {
    uint32_t word = w[wi];
    while (word) {
      int b = __ffs(word) - 1;
      word &= word - 1;
      cols[pos++] = (uint16_t)(lane * 128 + wi * 32 + b);
    }
  }
}

// ---- dinv[i] = f32 rsqrt(1 + surviving-degree); mask==null => all survive ----
__global__ __launch_bounds__(256) void k_dinv(const uint32_t* __restrict__ rowptr,
                                              const uint8_t* __restrict__ mask,
                                              float* __restrict__ dinv) {
  int lane = threadIdx.x & 63;
  int i = blockIdx.x * 4 + (threadIdx.x >> 6);
  uint32_t s0 = rowptr[i], s1 = rowptr[i + 1];
  int c = 0;
  for (uint32_t e = s0 + lane; e < s1; e += 64) c += mask ? (int)mask[e] : 1;
  for (int s = 32; s; s >>= 1) c += __shfl_xor(c, s, 64);
  if (lane == 0) dinv[i] = (float)(1.0 / sqrt((double)(c + 1)));
}

// ---- H = A(NNxK) @ W(KxN): f64 accumulate, rounded to f32 (ref's h is f32) ----
template<int K, int N>
__global__ __launch_bounds__(256) void k_gemm(const float* __restrict__ A,
                                              const float* __restrict__ Wb,
                                              float* __restrict__ H) {
  int t = blockIdx.x * 256 + threadIdx.x;
  int i = t / N, c = t % N;
  double acc = 0.0;
#pragma unroll 8
  for (int k = 0; k < K; ++k)
    acc += (double)A[(size_t)i * K + k] * (double)Wb[(size_t)k * N + c];
  H[t] = (float)acc;
}

// ---- z_i = dropout(relu(sum_j f32(di*dj)*h_j + f32(di*di)*h_i + b)) ----
// coefficient per edge matches ref's elementwise f32: dinv[:,None]*a*dinv[None,:]
template<int D>
__global__ __launch_bounds__(256) void k_agg(const uint32_t* __restrict__ rowptr,
                                             const uint16_t* __restrict__ cols,
                                             const uint8_t* __restrict__ mask,
                                             const float* __restrict__ h,
                                             const float* __restrict__ dinv,
                                             const float* __restrict__ bias,
                                             TFKey kd, float* __restrict__ zout) {
  int lane = threadIdx.x & 63;
  int i = blockIdx.x * 4 + (threadIdx.x >> 6);
  bool act = lane < D;
  float di = dinv[i];
  uint32_t s0 = rowptr[i], s1 = rowptr[i + 1];
  double acc = 0.0;
  for (uint32_t e = s0; e < s1; ++e) {        // ~32 iters; broadcast loads
    if (mask && !mask[e]) continue;
    int j = cols[e];
    if (act) {
      float c = di * dinv[j];                 // f32 round, as ref's elementwise
      acc += (double)c * (double)h[(size_t)j * D + lane];
    }
  }
  if (act) {
    float cI = di * di;                       // +I diagonal term, f32
    acc += (double)cI * (double)h[(size_t)i * D + lane];
    float s = (float)acc;                     // matmul result rounded f32
    float pre = s + bias[lane];               // f32 bias add
    pre = fmaxf(pre, 0.0f);                   // relu
    float u = tf_uniform(kd, (uint32_t)(i * D + lane));
    float val = (u < 0.9f) ? (pre / 0.9f) : 0.0f;   // dropout, all-f32
    zout[(size_t)i * D + lane] = val;
  }
}

// ---- mask[e] = uniform(kb)[i*8192+j] < f32 sigmoid(f32(z_i . z_j)) ----
__global__ __launch_bounds__(256) void k_sample(const uint32_t* __restrict__ rowptr,
                                                const uint16_t* __restrict__ cols,
                                                const float* __restrict__ z,
                                                TFKey kb,
                                                uint8_t* __restrict__ mask) {
  int lane = threadIdx.x & 63;
  int i = blockIdx.x * 4 + (threadIdx.x >> 6);
  double zi = (double)z[(size_t)i * 64 + lane];
  uint32_t s0 = rowptr[i], s1 = rowptr[i + 1];
  for (uint32_t e = s0; e < s1; ++e) {
    int j = cols[e];
    double p = zi * (double)z[(size_t)j * 64 + lane];
    for (int s = 32; s >= 1; s >>= 1) p += __shfl_xor(p, s, 64);
    float dot32 = (float)p;                   // ref's f32 z@z.T entry
    float prob = (float)(1.0 / (1.0 + exp(-(double)dot32)));  // f32 sigmoid
    uint32_t n = ((uint32_t)i << 13) | (uint32_t)j;
    float u = tf_uniform(kb, n);
    if (lane == 0) mask[e] = (u < prob) ? 1u : 0u;
  }
}

extern "C" void kernel_launch(void* const* d_in, const int* in_sizes, int n_in,
                              void* d_out, int out_size, void* d_ws, size_t ws_size,
                              hipStream_t stream) {
  (void)in_sizes; (void)n_in; (void)out_size; (void)ws_size;
  const float* x  = (const float*)d_in[0];   // f32 per reference dtypes
  const float* W0 = (const float*)d_in[1];
  const float* b0 = (const float*)d_in[2];
  const float* W1 = (const float*)d_in[3];
  const float* b1 = (const float*)d_in[4];
  const float* W2 = (const float*)d_in[5];
  const float* b2 = (const float*)d_in[6];
  const int* ei = (const int*)d_in[7];
  float* out = (float*)d_out;                // OUTPUT IS FLOAT32 (ref returns f32 z)

  // Workspace (~9.4 MB): dense bitmask dies after k_fill; f32 h/z overlay it
  uint8_t* base = (uint8_t*)d_ws;
  uint32_t* dense = (uint32_t*)(base);                      // [0, 8 MB) build
  float* h        = (float*)(base);                         // [0, 2 MB) layers
  float* z        = (float*)(base + 2097152);               // [2, 4 MB)
  uint32_t* rowptr= (uint32_t*)(base + 8388608);            // 8193*4 B
  uint32_t* deg   = (uint32_t*)(base + 8388608 + 65536);
  uint16_t* cols  = (uint16_t*)(base + 8388608 + 131072);   // 512 KB
  uint8_t*  mask  = (uint8_t*)(base + 8388608 + 655360);    // 256 KB
  float*    dinv  = (float*)(base + 8388608 + 917504);      // 32 KB
  uint32_t* flag  = (uint32_t*)(base + 8388608 + 983040);   // 4 B

  // JAX partitionable key chain: k_i = fold_in(key(42), i) = cipher((0,42),(0,i));
  // foldlike split: kd = full pair @ (0,0), kb = full pair @ (0,1)
  TFKey kd[3], kb[3];
  for (uint32_t i = 0; i < 3; ++i) {
    uint32_t la, lb;
    tf2x32(0u, 42u, 0u, i, &la, &lb);
    tf2x32(la, lb, 0u, 0u, &kd[i].a, &kd[i].b);
    tf2x32(la, lb, 0u, 1u, &kb[i].a, &kb[i].b);
  }

  (void)hipMemsetAsync(dense, 0, (size_t)NN * WPR * 4, stream);
  (void)hipMemsetAsync(flag, 0, 4, stream);
  k_probe<<<NE / 256, 256, 0, stream>>>(ei, flag);
  k_build<<<NE / 256, 256, 0, stream>>>(ei, flag, dense);
  k_deg  <<<NN / 4, 256, 0, stream>>>(dense, deg);
  k_scan <<<1, 256, 0, stream>>>(deg, rowptr);
  k_fill <<<NN / 4, 256, 0, stream>>>(dense, rowptr, cols);
  // dense dead; h/z overlay it

  // layer 0 (all original edges)
  k_dinv<<<NN / 4, 256, 0, stream>>>(rowptr, nullptr, dinv);
  k_gemm<128, 64><<<NN * 64 / 256, 256, 0, stream>>>(x, W0, h);
  k_agg<64><<<NN / 4, 256, 0, stream>>>(rowptr, cols, nullptr, h, dinv, b0, kd[0], z);
  k_sample<<<NN / 4, 256, 0, stream>>>(rowptr, cols, z, kb[0], mask);

  // layer 1 (edges masked by sample 0)
  k_dinv<<<NN / 4, 256, 0, stream>>>(rowptr, mask, dinv);
  k_gemm<64, 64><<<NN * 64 / 256, 256, 0, stream>>>(z, W1, h);
  k_agg<64><<<NN / 4, 256, 0, stream>>>(rowptr, cols, mask, h, dinv, b1, kd[1], z);
  k_sample<<<NN / 4, 256, 0, stream>>>(rowptr, cols, z, kb[1], mask);

  // layer 2 (edges masked by sample 1) -> f32 output
  k_dinv<<<NN / 4, 256, 0, stream>>>(rowptr, mask, dinv);
  k_gemm<64, 32><<<NN * 32 / 256, 256, 0, stream>>>(z, W2, h);
  k_agg<32><<<NN / 4, 256, 0, stream>>>(rowptr, cols, mask, h, dinv, b2, kd[2], out);
}

// Round 11
// 230.066 us; speedup vs baseline: 1.8882x; 1.8882x over previous
//
#include <hip/hip_runtime.h>
#include <stdint.h>
#include <math.h>

#define NN 8192        // nodes
#define NE 262144      // edges
#define WPR 256        // 32-bit words per dense adjacency row

struct TFKey { uint32_t a, b; };

// JAX threefry2x32 (rot 13,15,26,6 / 17,29,16,24; 20 rounds)
__host__ __device__ static inline void tf2x32(uint32_t k0, uint32_t k1,
                                              uint32_t x0, uint32_t x1,
                                              uint32_t* o0, uint32_t* o1) {
  uint32_t ks2 = k0 ^ k1 ^ 0x1BD11BDAu;
#define TF_ROT(x, r) (((x) << (r)) | ((x) >> (32 - (r))))
#define TF_R(r) { x0 += x1; x1 = TF_ROT(x1, r); x1 ^= x0; }
  x0 += k0; x1 += k1;
  TF_R(13) TF_R(15) TF_R(26) TF_R(6)
  x0 += k1;  x1 += ks2 + 1u;
  TF_R(17) TF_R(29) TF_R(16) TF_R(24)
  x0 += ks2; x1 += k0 + 2u;
  TF_R(13) TF_R(15) TF_R(26) TF_R(6)
  x0 += k0;  x1 += k1 + 3u;
  TF_R(17) TF_R(29) TF_R(16) TF_R(24)
  x0 += k1;  x1 += ks2 + 4u;
  TF_R(13) TF_R(15) TF_R(26) TF_R(6)
  x0 += ks2; x1 += k0 + 5u;
  *o0 = x0; *o1 = x1;
#undef TF_R
#undef TF_ROT
}

// JAX partitionable 32-bit random_bits at flat index n: bits = o0^o1 @ (0,n);
// uniform f32 = bitcast((bits>>9)|0x3f800000) - 1.0f  (exact 2^-23 grid)
__device__ static inline float tf_uniform(TFKey k, uint32_t n) {
  uint32_t o0, o1;
  tf2x32(k.a, k.b, 0u, n, &o0, &o1);
  uint32_t bits = o0 ^ o1;
  return __uint_as_float((bits >> 9) | 0x3f800000u) - 1.0f;
}

// ---- probe edge_index storage: int64 (all vals < 8192) vs int32; 1 block ----
__global__ __launch_bounds__(256) void k_probe(const int* __restrict__ e,
                                               uint32_t* __restrict__ flag) {
  const unsigned long long* p = (const unsigned long long*)e;
  bool bad = false;
  for (int q = 0; q < 8; ++q)                 // 2048 u64 samples: decisive
    bad |= (p[threadIdx.x * 8 + q] >= 8192ull);
  if (__ballot(bad)) { if ((threadIdx.x & 63) == 0) atomicOr(flag, 1u); }
}

// ---- dense binary adjacency bitmask (dedupes duplicate edges) ----
__global__ __launch_bounds__(256) void k_build(const int* __restrict__ e,
                                               const uint32_t* __restrict__ flag,
                                               uint32_t* __restrict__ dense) {
  int ed = blockIdx.x * 256 + threadIdx.x;
  int r, c;
  if (*flag) { r = e[ed]; c = e[ed + NE]; }
  else { const long long* p = (const long long*)e; r = (int)p[ed]; c = (int)p[ed + NE]; }
  atomicOr(&dense[(size_t)r * WPR + (c >> 5)], 1u << (c & 31));
}

// ---- deg[i] = popcount(dense row i); wave-per-row ----
__global__ __launch_bounds__(256) void k_deg(const uint32_t* __restrict__ dense,
                                             uint32_t* __restrict__ deg) {
  int lane = threadIdx.x & 63;
  int i = blockIdx.x * 4 + (threadIdx.x >> 6);
  const uint4* row = (const uint4*)(dense + (size_t)i * WPR);
  uint4 v = row[lane];
  int c = __popc(v.x) + __popc(v.y) + __popc(v.z) + __popc(v.w);
  for (int s = 32; s; s >>= 1) c += __shfl_xor(c, s, 64);
  if (lane == 0) deg[i] = (uint32_t)c;
}

// ---- exclusive scan of deg[8192] -> rowptr[8193]; single block ----
__global__ __launch_bounds__(256) void k_scan(const uint32_t* __restrict__ deg,
                                              uint32_t* __restrict__ rowptr) {
  __shared__ uint32_t part[256];
  int t = threadIdx.x;
  uint32_t loc[32];
  uint32_t s = 0;
  for (int k = 0; k < 32; ++k) { loc[k] = s; s += deg[t * 32 + k]; }
  part[t] = s;
  __syncthreads();
  for (int off = 1; off < 256; off <<= 1) {
    uint32_t v = (t >= off) ? part[t - off] : 0u;
    __syncthreads();
    part[t] += v;
    __syncthreads();
  }
  uint32_t base = (t == 0) ? 0u : part[t - 1];
  for (int k = 0; k < 32; ++k) rowptr[t * 32 + k] = base + loc[k];
  if (t == 255) rowptr[8192] = part[255];
}

// ---- CSR cols+rows from dense bitmask; wave-per-row, ascending cols ----
__global__ __launch_bounds__(256) void k_fill(const uint32_t* __restrict__ dense,
                                              const uint32_t* __restrict__ rowptr,
                                              uint16_t* __restrict__ cols,
                                              uint16_t* __restrict__ rows) {
  int lane = threadIdx.x & 63;
  int i = blockIdx.x * 4 + (threadIdx.x >> 6);
  const uint4* row = (const uint4*)(dense + (size_t)i * WPR);
  uint4 v = row[lane];
  uint32_t w[4] = { v.x, v.y, v.z, v.w };
  int cnt = __popc(w[0]) + __popc(w[1]) + __popc(w[2]) + __popc(w[3]);
  int pre = cnt;
  for (int s = 1; s < 64; s <<= 1) {
    int o = __shfl_up(pre, s, 64);
    if (lane >= s) pre += o;
  }
  pre -= cnt;
  uint32_t pos = rowptr[i] + (uint32_t)pre;
  for (int wi = 0; wi < 4; ++wi) {
    uint32_t word = w[wi];
    while (word) {
      int b = __ffs(word) - 1;
      word &= word - 1;
      cols[pos] = (uint16_t)(lane * 128 + wi * 32 + b);
      rows[pos] = (uint16_t)i;
      ++pos;
    }
  }
}

// ---- fused: blocks [0,GB) do H = A@W (f64 acc -> f32); blocks [GB,GB+NN/4)
//      do dinv[i] = f32 rsqrt(1 + surviving-degree). Independent workloads. ----
template<int K, int N>
__global__ __launch_bounds__(256) void k_dg(const float* __restrict__ A,
                                            const float* __restrict__ Wb,
                                            float* __restrict__ H,
                                            const uint32_t* __restrict__ rowptr,
                                            const uint8_t* __restrict__ mask,
                                            float* __restrict__ dinv) {
  constexpr int GB = NN * N / 256;
  if (blockIdx.x < GB) {
    int t = blockIdx.x * 256 + threadIdx.x;
    int i = t / N, c = t % N;
    double a0 = 0.0, a1 = 0.0;
#pragma unroll 8
    for (int k = 0; k < K; k += 2) {
      a0 += (double)A[(size_t)i * K + k] * (double)Wb[(size_t)k * N + c];
      a1 += (double)A[(size_t)i * K + k + 1] * (double)Wb[(size_t)(k + 1) * N + c];
    }
    H[t] = (float)(a0 + a1);
  } else {
    int lane = threadIdx.x & 63;
    int i = (blockIdx.x - GB) * 4 + (threadIdx.x >> 6);
    uint32_t s0 = rowptr[i], s1 = rowptr[i + 1];
    int c = 0;
    for (uint32_t e = s0 + lane; e < s1; e += 64) c += mask ? (int)mask[e] : 1;
    for (int s = 32; s; s >>= 1) c += __shfl_xor(c, s, 64);
    if (lane == 0) dinv[i] = (float)(1.0 / sqrt((double)(c + 1)));
  }
}

// ---- z_i = dropout(relu(sum_j f32(di*dj)*h_j + f32(di*di)*h_i + b)) ----
template<int D>
__global__ __launch_bounds__(256) void k_agg(const uint32_t* __restrict__ rowptr,
                                             const uint16_t* __restrict__ cols,
                                             const uint8_t* __restrict__ mask,
                                             const float* __restrict__ h,
                                             const float* __restrict__ dinv,
                                             const float* __restrict__ bias,
                                             TFKey kd, float* __restrict__ zout) {
  int lane = threadIdx.x & 63;
  int i = blockIdx.x * 4 + (threadIdx.x >> 6);
  bool act = lane < D;
  float di = dinv[i];
  uint32_t s0 = rowptr[i], s1 = rowptr[i + 1];
  double a0 = 0.0, a1 = 0.0;
  uint32_t e = s0;
  for (; e + 1 < s1; e += 2) {                // 2 accumulators: half the chain
    int j0 = cols[e], j1 = cols[e + 1];
    bool m0 = !mask || mask[e], m1 = !mask || mask[e + 1];
    if (act) {
      if (m0) { float c0 = di * dinv[j0]; a0 += (double)c0 * (double)h[(size_t)j0 * D + lane]; }
      if (m1) { float c1 = di * dinv[j1]; a1 += (double)c1 * (double)h[(size_t)j1 * D + lane]; }
    }
  }
  if (e < s1 && (!mask || mask[e]) && act) {
    int j = cols[e];
    float c = di * dinv[j];
    a0 += (double)c * (double)h[(size_t)j * D + lane];
  }
  if (act) {
    double acc = a0 + a1;
    float cI = di * di;                       // +I diagonal term, f32
    acc += (double)cI * (double)h[(size_t)i * D + lane];
    float s = (float)acc;                     // matmul result rounded f32
    float pre = fmaxf(s + bias[lane], 0.0f);  // bias + relu (f32)
    float u = tf_uniform(kd, (uint32_t)(i * D + lane));
    zout[(size_t)i * D + lane] = (u < 0.9f) ? (pre / 0.9f) : 0.0f;
  }
}

// ---- edge-parallel resample: lane-per-edge, f64 dot via float4 loads ----
__global__ __launch_bounds__(256) void k_sample_e(const uint32_t* __restrict__ rowptr,
                                                  const uint16_t* __restrict__ rows,
                                                  const uint16_t* __restrict__ cols,
                                                  const float* __restrict__ z,
                                                  TFKey kb,
                                                  uint8_t* __restrict__ mask) {
  uint32_t e = blockIdx.x * 256 + threadIdx.x;
  uint32_t nnz = rowptr[8192];
  if (e >= nnz) return;
  uint32_t i = rows[e], j = cols[e];
  const float4* zi = (const float4*)(z + (size_t)i * 64);
  const float4* zj = (const float4*)(z + (size_t)j * 64);
  double p0 = 0.0, p1 = 0.0, p2 = 0.0, p3 = 0.0;
#pragma unroll
  for (int q = 0; q < 16; q += 2) {
    float4 a = zi[q], b = zj[q];
    float4 c = zi[q + 1], d = zj[q + 1];
    p0 += (double)a.x * (double)b.x + (double)a.y * (double)b.y;
    p1 += (double)a.z * (double)b.z + (double)a.w * (double)b.w;
    p2 += (double)c.x * (double)d.x + (double)c.y * (double)d.y;
    p3 += (double)c.z * (double)d.z + (double)c.w * (double)d.w;
  }
  double p = (p0 + p1) + (p2 + p3);
  float dot32 = (float)p;                     // ref's f32 z@z.T entry
  float prob = (float)(1.0 / (1.0 + exp(-(double)dot32)));  // identical formula
  uint32_t n = (i << 13) | j;                 // flat index i*8192+j
  float u = tf_uniform(kb, n);
  mask[e] = (u < prob) ? 1u : 0u;
}

extern "C" void kernel_launch(void* const* d_in, const int* in_sizes, int n_in,
                              void* d_out, int out_size, void* d_ws, size_t ws_size,
                              hipStream_t stream) {
  (void)in_sizes; (void)n_in; (void)out_size; (void)ws_size;
  const float* x  = (const float*)d_in[0];
  const float* W0 = (const float*)d_in[1];
  const float* b0 = (const float*)d_in[2];
  const float* W1 = (const float*)d_in[3];
  const float* b1 = (const float*)d_in[4];
  const float* W2 = (const float*)d_in[5];
  const float* b2 = (const float*)d_in[6];
  const int* ei = (const int*)d_in[7];
  float* out = (float*)d_out;                // output is float32

  // Workspace (~9.9 MB): dense bitmask dies after k_fill; f32 h/z overlay it
  uint8_t* base = (uint8_t*)d_ws;
  uint32_t* dense = (uint32_t*)(base);                       // [0, 8 MB) build
  float* h        = (float*)(base);                          // [0, 2 MB) layers
  float* z        = (float*)(base + 2097152);                // [2, 4 MB)
  uint32_t* rowptr= (uint32_t*)(base + 8388608);             // 64 KB slot
  uint32_t* deg   = (uint32_t*)(base + 8388608 + 65536);     // 64 KB slot
  uint16_t* cols  = (uint16_t*)(base + 8388608 + 131072);    // 512 KB
  uint16_t* rows  = (uint16_t*)(base + 8388608 + 655360);    // 512 KB
  uint8_t*  mask  = (uint8_t*)(base + 8388608 + 1179648);    // 256 KB
  float*    dinv  = (float*)(base + 8388608 + 1441792);      // 32 KB
  uint32_t* flag  = (uint32_t*)(base + 8388608 + 1474560);   // 4 B

  // JAX partitionable key chain: k_i = fold_in(key(42), i) = cipher((0,42),(0,i));
  // foldlike split: kd = full pair @ (0,0), kb = full pair @ (0,1)
  TFKey kd[3], kb[3];
  for (uint32_t i = 0; i < 3; ++i) {
    uint32_t la, lb;
    tf2x32(0u, 42u, 0u, i, &la, &lb);
    tf2x32(la, lb, 0u, 0u, &kd[i].a, &kd[i].b);
    tf2x32(la, lb, 0u, 1u, &kb[i].a, &kb[i].b);
  }

  (void)hipMemsetAsync(dense, 0, (size_t)NN * WPR * 4, stream);
  (void)hipMemsetAsync(flag, 0, 4, stream);
  k_probe<<<1, 256, 0, stream>>>(ei, flag);
  k_build<<<NE / 256, 256, 0, stream>>>(ei, flag, dense);
  k_deg  <<<NN / 4, 256, 0, stream>>>(dense, deg);
  k_scan <<<1, 256, 0, stream>>>(deg, rowptr);
  k_fill <<<NN / 4, 256, 0, stream>>>(dense, rowptr, cols, rows);
  // dense dead; h/z overlay it

  // layer 0: fused {gemm x@W0, dinv(all edges)}, then agg, then resample
  k_dg<128, 64><<<NN * 64 / 256 + NN / 4, 256, 0, stream>>>(x, W0, h, rowptr, nullptr, dinv);
  k_agg<64><<<NN / 4, 256, 0, stream>>>(rowptr, cols, nullptr, h, dinv, b0, kd[0], z);
  k_sample_e<<<NE / 256, 256, 0, stream>>>(rowptr, rows, cols, z, kb[0], mask);

  // layer 1
  k_dg<64, 64><<<NN * 64 / 256 + NN / 4, 256, 0, stream>>>(z, W1, h, rowptr, mask, dinv);
  k_agg<64><<<NN / 4, 256, 0, stream>>>(rowptr, cols, mask, h, dinv, b1, kd[1], z);
  k_sample_e<<<NE / 256, 256, 0, stream>>>(rowptr, rows, cols, z, kb[1], mask);

  // layer 2 -> f32 output
  k_dg<64, 32><<<NN * 32 / 256 + NN / 4, 256, 0, stream>>>(z, W2, h, rowptr, mask, dinv);
  k_agg<32><<<NN / 4, 256, 0, stream>>>(rowptr, cols, mask, h, dinv, b2, kd[2], out);
}